// Round 1
// baseline (831.012 us; speedup 1.0000x reference)
//
#include <hip/hip_runtime.h>

#define IN_SIZE 4096
#define OUT_SIZE 4096
#define BATCH 256
#define NNZ ((IN_SIZE * OUT_SIZE) / 2)   // 8388608

// ---------------------------------------------------------------------------
// Kernel 1: scatter COO -> dense W [IN_SIZE][OUT_SIZE], duplicates accumulate.
// idx layout (row-major [NNZ,2]): idx[2i] = input row r, idx[2i+1] = output col c.
// ---------------------------------------------------------------------------
__global__ __launch_bounds__(256) void scatter_kernel(const int* __restrict__ idx,
                                                      const float* __restrict__ val,
                                                      float* __restrict__ W) {
    const int i = blockIdx.x * 256 + threadIdx.x;
    // NNZ is an exact multiple of 256, but keep the guard cheap and safe.
    if (i < NNZ) {
        const int2 rc = reinterpret_cast<const int2*>(idx)[i];  // coalesced 8B
        atomicAdd(&W[rc.x * OUT_SIZE + rc.y], val[i]);
    }
}

// ---------------------------------------------------------------------------
// Kernel 2: Z = relu(X @ W + bias)
// X: [BATCH][IN_SIZE] fp32, W: [IN_SIZE][OUT_SIZE] fp32, Z: [BATCH][OUT_SIZE]
// 64x64 block tile, BK=16, 256 threads, 4x4 micro-tile per thread. fp32 VALU
// (no fp32-input MFMA on CDNA4).
// ---------------------------------------------------------------------------
__global__ __launch_bounds__(256) void gemm_bias_relu(const float* __restrict__ X,
                                                      const float* __restrict__ W,
                                                      const float* __restrict__ bias,
                                                      float* __restrict__ Z) {
    const int bm = blockIdx.y * 64;
    const int bn = blockIdx.x * 64;

    __shared__ float As[16][65];  // [k][m], +1 pad to break write conflicts
    __shared__ float Bs[16][64];  // [k][n]

    const int tid = threadIdx.x;
    const int tm = (tid >> 4) << 2;   // 0..60
    const int tn = (tid & 15) << 2;   // 0..60

    float acc[4][4];
#pragma unroll
    for (int i = 0; i < 4; i++)
#pragma unroll
        for (int j = 0; j < 4; j++) acc[i][j] = 0.f;

    for (int k0 = 0; k0 < IN_SIZE; k0 += 16) {
        // Load A tile: 64 rows x 16 k. flat = tid + 256*j ; r = flat/16, c = flat%16
#pragma unroll
        for (int j = 0; j < 4; j++) {
            const int f = tid + 256 * j;
            const int r = f >> 4, c = f & 15;
            As[c][r] = X[(bm + r) * IN_SIZE + (k0 + c)];
        }
        // Load B tile: 16 k x 64 n. flat = tid + 256*j ; r = flat/64, c = flat%64
#pragma unroll
        for (int j = 0; j < 4; j++) {
            const int f = tid + 256 * j;
            const int r = f >> 6, c = f & 63;
            Bs[r][c] = W[(k0 + r) * OUT_SIZE + (bn + c)];
        }
        __syncthreads();

#pragma unroll
        for (int kk = 0; kk < 16; kk++) {
            const float a0 = As[kk][tm + 0];
            const float a1 = As[kk][tm + 1];
            const float a2 = As[kk][tm + 2];
            const float a3 = As[kk][tm + 3];
            const float4 b = *reinterpret_cast<const float4*>(&Bs[kk][tn]);
            acc[0][0] += a0 * b.x; acc[0][1] += a0 * b.y; acc[0][2] += a0 * b.z; acc[0][3] += a0 * b.w;
            acc[1][0] += a1 * b.x; acc[1][1] += a1 * b.y; acc[1][2] += a1 * b.z; acc[1][3] += a1 * b.w;
            acc[2][0] += a2 * b.x; acc[2][1] += a2 * b.y; acc[2][2] += a2 * b.z; acc[2][3] += a2 * b.w;
            acc[3][0] += a3 * b.x; acc[3][1] += a3 * b.y; acc[3][2] += a3 * b.z; acc[3][3] += a3 * b.w;
        }
        __syncthreads();
    }

    // Epilogue: bias + relu, vector store
    const float4 bv = *reinterpret_cast<const float4*>(&bias[bn + tn]);
#pragma unroll
    for (int i = 0; i < 4; i++) {
        float4 o;
        o.x = fmaxf(acc[i][0] + bv.x, 0.f);
        o.y = fmaxf(acc[i][1] + bv.y, 0.f);
        o.z = fmaxf(acc[i][2] + bv.z, 0.f);
        o.w = fmaxf(acc[i][3] + bv.w, 0.f);
        *reinterpret_cast<float4*>(&Z[(bm + tm + i) * OUT_SIZE + (bn + tn)]) = o;
    }
}

extern "C" void kernel_launch(void* const* d_in, const int* in_sizes, int n_in,
                              void* d_out, int out_size, void* d_ws, size_t ws_size,
                              hipStream_t stream) {
    const float* X    = (const float*)d_in[0];   // [BATCH, IN_SIZE] fp32
    const int*   idx  = (const int*)d_in[1];     // [NNZ, 2] int32
    const float* val  = (const float*)d_in[2];   // [NNZ] fp32
    const float* bias = (const float*)d_in[3];   // [OUT_SIZE] fp32
    float* Z = (float*)d_out;                    // [BATCH, OUT_SIZE] fp32
    float* W = (float*)d_ws;                     // dense [IN_SIZE][OUT_SIZE] fp32 (64 MB)

    // Workspace is poisoned 0xAA before every call: must zero W in-graph.
    hipMemsetAsync(W, 0, (size_t)IN_SIZE * OUT_SIZE * sizeof(float), stream);

    scatter_kernel<<<NNZ / 256, 256, 0, stream>>>(idx, val, W);

    dim3 grid(OUT_SIZE / 64, BATCH / 64);
    gemm_bias_relu<<<grid, 256, 0, stream>>>(X, W, bias, Z);
}

// Round 2
// 642.335 us; speedup vs baseline: 1.2937x; 1.2937x over previous
//
#include <hip/hip_runtime.h>
#include <hip/hip_bf16.h>

#define IN_SIZE 4096
#define OUT_SIZE 4096
#define BATCH 256
#define NNZ ((IN_SIZE * OUT_SIZE) / 2)   // 8388608

typedef float f32x4 __attribute__((ext_vector_type(4)));
typedef short s16x8 __attribute__((ext_vector_type(8)));

// ---------------------------------------------------------------------------
// Kernel 1: scatter COO -> dense TRANSPOSED W:  Wt[out_col][in_row] (fp32).
// Grid-stride with 4-deep batched atomics: tests whether the 408us scatter was
// wave-drain/ILP-limited or memory-system atomic-rate-limited.
// ---------------------------------------------------------------------------
#define SC_BLOCKS 1024
__global__ __launch_bounds__(256) void scatter_t(const int2* __restrict__ idx2,
                                                 const float* __restrict__ val,
                                                 float* __restrict__ Wt) {
    const int stride = SC_BLOCKS * 256;
    int i = blockIdx.x * 256 + threadIdx.x;
    // NNZ / (4*stride) == 8 exactly
#pragma unroll 1
    for (int iter = 0; iter < NNZ / (4 * SC_BLOCKS * 256); ++iter) {
        const int2 e0 = idx2[i];
        const int2 e1 = idx2[i + stride];
        const int2 e2 = idx2[i + 2 * stride];
        const int2 e3 = idx2[i + 3 * stride];
        const float v0 = val[i];
        const float v1 = val[i + stride];
        const float v2 = val[i + 2 * stride];
        const float v3 = val[i + 3 * stride];
        atomicAdd(&Wt[e0.y * IN_SIZE + e0.x], v0);
        atomicAdd(&Wt[e1.y * IN_SIZE + e1.x], v1);
        atomicAdd(&Wt[e2.y * IN_SIZE + e2.x], v2);
        atomicAdd(&Wt[e3.y * IN_SIZE + e3.x], v3);
        i += 4 * stride;
    }
}

// ---------------------------------------------------------------------------
// Kernel 2: Z = relu(X @ W + bias) via bf16 MFMA, LDS-free.
// X:  [BATCH][IN_SIZE] fp32 (A operand, rows m, k contiguous)
// Wt: [OUT_SIZE][IN_SIZE] fp32 (B operand transposed: row n, k contiguous)
// Fragment mapping (guide §3, m89-verified):
//   A: lane l holds A[l&15][(l>>4)*8 + j], j=0..7
//   B: lane l holds B[(l>>4)*8 + j][l&15]
//   D: reg r -> row (l>>4)*4 + r, col l&15
// ---------------------------------------------------------------------------
__device__ __forceinline__ short bfbits(float f) {
    __hip_bfloat16 h = __float2bfloat16(f);
    return __builtin_bit_cast(short, h);
}

__device__ __forceinline__ s16x8 pack8(f32x4 lo, f32x4 hi) {
    s16x8 r;
    r[0] = bfbits(lo[0]); r[1] = bfbits(lo[1]); r[2] = bfbits(lo[2]); r[3] = bfbits(lo[3]);
    r[4] = bfbits(hi[0]); r[5] = bfbits(hi[1]); r[6] = bfbits(hi[2]); r[7] = bfbits(hi[3]);
    return r;
}

__global__ __launch_bounds__(256) void gemm_mfma(const float* __restrict__ X,
                                                 const float* __restrict__ Wt,
                                                 const float* __restrict__ bias,
                                                 float* __restrict__ Z) {
    const int l  = threadIdx.x & 63;
    const int w  = threadIdx.x >> 6;          // wave 0..3
    const int bm = blockIdx.y * 128;          // batch-row tile
    const int bn = blockIdx.x * 32;           // out-col tile
    const int lr = l & 15;                    // row/col within fragment
    const int kg = (l >> 4) * 8;              // per-lane k offset

    const float* pA[2];
    const float* pB[2];
#pragma unroll
    for (int mi = 0; mi < 2; ++mi)
        pA[mi] = X + (bm + w * 32 + mi * 16 + lr) * IN_SIZE + kg;
#pragma unroll
    for (int ni = 0; ni < 2; ++ni)
        pB[ni] = Wt + (bn + ni * 16 + lr) * IN_SIZE + kg;

    f32x4 acc[2][2] = {};

#pragma unroll 2
    for (int k0 = 0; k0 < IN_SIZE; k0 += 32) {
        s16x8 a[2], b[2];
#pragma unroll
        for (int mi = 0; mi < 2; ++mi) {
            const f32x4 lo = *reinterpret_cast<const f32x4*>(pA[mi]);
            const f32x4 hi = *reinterpret_cast<const f32x4*>(pA[mi] + 4);
            a[mi] = pack8(lo, hi);
            pA[mi] += 32;
        }
#pragma unroll
        for (int ni = 0; ni < 2; ++ni) {
            const f32x4 lo = *reinterpret_cast<const f32x4*>(pB[ni]);
            const f32x4 hi = *reinterpret_cast<const f32x4*>(pB[ni] + 4);
            b[ni] = pack8(lo, hi);
            pB[ni] += 32;
        }
#pragma unroll
        for (int mi = 0; mi < 2; ++mi)
#pragma unroll
            for (int ni = 0; ni < 2; ++ni)
                acc[mi][ni] = __builtin_amdgcn_mfma_f32_16x16x32_bf16(
                    a[mi], b[ni], acc[mi][ni], 0, 0, 0);
    }

    // Epilogue: bias + relu
#pragma unroll
    for (int mi = 0; mi < 2; ++mi) {
#pragma unroll
        for (int ni = 0; ni < 2; ++ni) {
            const int col = bn + ni * 16 + lr;
            const float bv = bias[col];
            const int r0 = bm + w * 32 + mi * 16 + ((l >> 4) << 2);
#pragma unroll
            for (int rr = 0; rr < 4; ++rr) {
                Z[(r0 + rr) * OUT_SIZE + col] = fmaxf(acc[mi][ni][rr] + bv, 0.f);
            }
        }
    }
}

extern "C" void kernel_launch(void* const* d_in, const int* in_sizes, int n_in,
                              void* d_out, int out_size, void* d_ws, size_t ws_size,
                              hipStream_t stream) {
    const float* X    = (const float*)d_in[0];   // [BATCH, IN_SIZE] fp32
    const int*   idx  = (const int*)d_in[1];     // [NNZ, 2] int32 (harness-canonicalized)
    const float* val  = (const float*)d_in[2];   // [NNZ] fp32
    const float* bias = (const float*)d_in[3];   // [OUT_SIZE] fp32
    float* Z  = (float*)d_out;                   // [BATCH, OUT_SIZE] fp32
    float* Wt = (float*)d_ws;                    // dense transposed W [OUT][IN] fp32, 64 MB

    hipMemsetAsync(Wt, 0, (size_t)IN_SIZE * OUT_SIZE * sizeof(float), stream);

    scatter_t<<<SC_BLOCKS, 256, 0, stream>>>((const int2*)idx, val, Wt);

    dim3 grid(OUT_SIZE / 32, BATCH / 128);
    gemm_mfma<<<grid, 256, 0, stream>>>(X, Wt, bias, Z);
}

// Round 3
// 338.174 us; speedup vs baseline: 2.4573x; 1.8994x over previous
//
#include <hip/hip_runtime.h>
#include <hip/hip_bf16.h>

#define IN_SIZE 4096
#define OUT_SIZE 4096
#define BATCH 256
#define NNZ ((IN_SIZE * OUT_SIZE) / 2)   // 8388608

// Binning config: 512 buckets, bucket b = Wt rows [8b, 8b+8)  (Wt = W^T [out][in])
#define NB    512
#define EPB   (NNZ / NB)       // 16384 elements per binning block
#define CHUNK 4096
#define NCH   (EPB / CHUNK)    // 4
#define EPT   (CHUNK / 256)    // 16

typedef float f32x4 __attribute__((ext_vector_type(4)));
typedef short s16x8 __attribute__((ext_vector_type(8)));

// ---- workspace layout (bytes) ----
static const size_t OFF_XBF  = 0;                               // X bf16: 256*4096*2 = 2 MB
static const size_t OFF_WTBF = (size_t)2 << 20;                 // Wt bf16: 32 MB
static const size_t OFF_PART = (size_t)34 << 20;                // 4 partials * 4 MB = 16 MB
static const size_t OFF_BIN  = (size_t)50 << 20;                // binned: NNZ*8 = 64 MB
static const size_t OFF_HIST = OFF_BIN + (size_t)NNZ * 8;       // 512*512*4 = 1 MB
static const size_t OFF_BPRE = OFF_HIST + (size_t)NB * NB * 4;  // 1 MB
static const size_t OFF_TOT  = OFF_BPRE + (size_t)NB * NB * 4;  // 2 KB
static const size_t OFF_BASE = OFF_TOT + (size_t)NB * 4;        // 2 KB
static const size_t WS_NEED  = OFF_BASE + (size_t)NB * 4;       // ~121.6 MB

__device__ __forceinline__ short bfbits(float f) {
    __hip_bfloat16 h = __float2bfloat16(f);
    return __builtin_bit_cast(short, h);
}
__device__ __forceinline__ s16x8 pack8(f32x4 lo, f32x4 hi) {
    s16x8 r;
    r[0] = bfbits(lo[0]); r[1] = bfbits(lo[1]); r[2] = bfbits(lo[2]); r[3] = bfbits(lo[3]);
    r[4] = bfbits(hi[0]); r[5] = bfbits(hi[1]); r[6] = bfbits(hi[2]); r[7] = bfbits(hi[3]);
    return r;
}

// Exclusive scan of 512 u32 in LDS h -> out. 256 threads. Returns grand total.
// Has a trailing __syncthreads().
__device__ __forceinline__ unsigned scan512(const unsigned* h, unsigned* out,
                                            unsigned* wsum, int t) {
    const int lane = t & 63, wid = t >> 6;
    const unsigned a0 = h[2 * t], a1 = h[2 * t + 1];
    const unsigned s = a0 + a1;
    unsigned inc = s;
#pragma unroll
    for (int d = 1; d < 64; d <<= 1) {
        const unsigned n = __shfl_up(inc, d);
        if (lane >= d) inc += n;
    }
    if (lane == 63) wsum[wid] = inc;
    __syncthreads();
    unsigned wpre = 0;
#pragma unroll
    for (int i = 0; i < 4; ++i)
        if (i < wid) wpre += wsum[i];
    const unsigned ex = wpre + inc - s;
    out[2 * t]     = ex;
    out[2 * t + 1] = ex + a0;
    const unsigned total = wsum[0] + wsum[1] + wsum[2] + wsum[3];
    __syncthreads();
    return total;
}

// ---------------------------------------------------------------------------
// K0: X fp32 -> bf16
// ---------------------------------------------------------------------------
__global__ __launch_bounds__(256) void k_xcvt(const float* __restrict__ X,
                                              s16x8* __restrict__ Xb) {
    const int i8 = blockIdx.x * 256 + threadIdx.x;  // 0..131071
    const f32x4 lo = reinterpret_cast<const f32x4*>(X)[2 * i8];
    const f32x4 hi = reinterpret_cast<const f32x4*>(X)[2 * i8 + 1];
    Xb[i8] = pack8(lo, hi);
}

// ---------------------------------------------------------------------------
// K1: per-block bucket histogram
// ---------------------------------------------------------------------------
__global__ __launch_bounds__(256) void k_hist(const int2* __restrict__ idx2,
                                              unsigned* __restrict__ hist) {
    __shared__ unsigned lh[NB];
    const int t = threadIdx.x, blk = blockIdx.x;
    lh[2 * t] = 0; lh[2 * t + 1] = 0;
    __syncthreads();
    const int base = blk * EPB;
#pragma unroll 8
    for (int j = 0; j < EPB / 256; ++j) {
        const int c = idx2[base + t + 256 * j].y;
        atomicAdd(&lh[((unsigned)c) >> 3], 1u);
    }
    __syncthreads();
    hist[blk * NB + t] = lh[t];
    hist[blk * NB + t + 256] = lh[t + 256];
}

// ---------------------------------------------------------------------------
// K2: per-bucket exclusive scan over blocks -> bpre[blk][b], totals[b]
// ---------------------------------------------------------------------------
__global__ __launch_bounds__(256) void k_scanblocks(const unsigned* __restrict__ hist,
                                                    unsigned* __restrict__ bpre,
                                                    unsigned* __restrict__ tot) {
    __shared__ unsigned h[NB], o[NB], wsum[4];
    const int t = threadIdx.x, b = blockIdx.x;
    h[2 * t]     = hist[(2 * t) * NB + b];
    h[2 * t + 1] = hist[(2 * t + 1) * NB + b];
    __syncthreads();
    const unsigned total = scan512(h, o, wsum, t);
    bpre[(2 * t) * NB + b]     = o[2 * t];
    bpre[(2 * t + 1) * NB + b] = o[2 * t + 1];
    if (t == 0) tot[b] = total;
}

// ---------------------------------------------------------------------------
// K3: exclusive scan of bucket totals -> bucket base offsets
// ---------------------------------------------------------------------------
__global__ __launch_bounds__(256) void k_scantot(const unsigned* __restrict__ tot,
                                                 unsigned* __restrict__ bbase) {
    __shared__ unsigned h[NB], o[NB], wsum[4];
    const int t = threadIdx.x;
    h[2 * t] = tot[2 * t]; h[2 * t + 1] = tot[2 * t + 1];
    __syncthreads();
    scan512(h, o, wsum, t);
    bbase[2 * t] = o[2 * t]; bbase[2 * t + 1] = o[2 * t + 1];
}

// ---------------------------------------------------------------------------
// K4: binned scatter with LDS reorder (coalesced writes, no global atomics)
// binned element: .x = pidx = (c&7)*4096 + r   .y = bits(val)
// ---------------------------------------------------------------------------
__global__ __launch_bounds__(256) void k_bin(const int2* __restrict__ idx2,
                                             const float* __restrict__ val,
                                             const unsigned* __restrict__ bpre,
                                             const unsigned* __restrict__ bbase,
                                             uint2* __restrict__ binned) {
    __shared__ unsigned cur[NB], hist[NB], start[NB], wsum[4];
    __shared__ unsigned st_dst[CHUNK], st_lo[CHUNK], st_hi[CHUNK];
    const int t = threadIdx.x, blk = blockIdx.x;
    cur[2 * t]     = bbase[2 * t]     + bpre[blk * NB + 2 * t];
    cur[2 * t + 1] = bbase[2 * t + 1] + bpre[blk * NB + 2 * t + 1];

    for (int ch = 0; ch < NCH; ++ch) {
        hist[2 * t] = 0; hist[2 * t + 1] = 0;
        __syncthreads();
        const int base = blk * EPB + ch * CHUNK;
        unsigned eb[EPT], er[EPT], elo[EPT], ehi[EPT];
#pragma unroll
        for (int j = 0; j < EPT; ++j) {
            const int i = base + t + 256 * j;
            const int2 rc = idx2[i];
            const float v = val[i];
            eb[j]  = ((unsigned)rc.y) >> 3;
            elo[j] = (unsigned)((rc.y & 7) * IN_SIZE + rc.x);
            ehi[j] = __float_as_uint(v);
            er[j]  = atomicAdd(&hist[eb[j]], 1u);
        }
        __syncthreads();
        scan512(hist, start, wsum, t);   // trailing barrier inside
#pragma unroll
        for (int j = 0; j < EPT; ++j) {
            const unsigned lp = start[eb[j]] + er[j];
            st_dst[lp] = cur[eb[j]] + er[j];
            st_lo[lp]  = elo[j];
            st_hi[lp]  = ehi[j];
        }
        __syncthreads();
        cur[2 * t]     += hist[2 * t];
        cur[2 * t + 1] += hist[2 * t + 1];
#pragma unroll
        for (int j = 0; j < EPT; ++j) {
            const int s = t + 256 * j;
            binned[st_dst[s]] = make_uint2(st_lo[s], st_hi[s]);
        }
        __syncthreads();
    }
}

// ---------------------------------------------------------------------------
// K5: per-bucket LDS accumulate -> Wt bf16 rows [8b, 8b+8)
// ---------------------------------------------------------------------------
__global__ __launch_bounds__(256) void k_accum(const uint2* __restrict__ binned,
                                               const unsigned* __restrict__ bbase,
                                               const unsigned* __restrict__ tot,
                                               s16x8* __restrict__ Wtb8) {
    __shared__ float acc[8 * IN_SIZE];   // 128 KB
    const int t = threadIdx.x, b = blockIdx.x;
    f32x4* a4 = reinterpret_cast<f32x4*>(acc);
#pragma unroll
    for (int j = 0; j < (8 * IN_SIZE / 4) / 256; ++j) a4[t + 256 * j] = (f32x4){0.f, 0.f, 0.f, 0.f};
    __syncthreads();
    const unsigned base = bbase[b], n = tot[b];
    for (unsigned i = t; i < n; i += 256) {
        const uint2 e = binned[base + i];
        atomicAdd(&acc[e.x], __uint_as_float(e.y));
    }
    __syncthreads();
    s16x8* dst = Wtb8 + (size_t)b * (8 * IN_SIZE / 8);
#pragma unroll
    for (int j = 0; j < (8 * IN_SIZE / 8) / 256; ++j) {
        const int i8 = t + 256 * j;
        const f32x4 lo = a4[2 * i8];
        const f32x4 hi = a4[2 * i8 + 1];
        dst[i8] = pack8(lo, hi);
    }
}

// ---------------------------------------------------------------------------
// K6: split-K bf16 MFMA GEMM: part[kz] = X[,:kchunk] @ Wt^T
// Fragment maps verified in round 2 (passed absmax):
//   A: lane l holds A[l&15][kg+j]; B: lane holds B[kg+j][l&15];
//   D: reg rr -> row (l>>4)*4+rr, col l&15
// ---------------------------------------------------------------------------
__global__ __launch_bounds__(256) void k_gemm(const short* __restrict__ A,
                                              const short* __restrict__ B,
                                              float* __restrict__ part) {
    const int l = threadIdx.x & 63, w = threadIdx.x >> 6;
    const int bm = blockIdx.y * 128, bn = blockIdx.x * 32, kz = blockIdx.z;
    const int lr = l & 15, kg = (l >> 4) * 8;
    const int kb = kz * (IN_SIZE / 4);

    const short* pA[2];
    const short* pB[2];
#pragma unroll
    for (int mi = 0; mi < 2; ++mi)
        pA[mi] = A + (size_t)(bm + w * 32 + mi * 16 + lr) * IN_SIZE + kb + kg;
#pragma unroll
    for (int ni = 0; ni < 2; ++ni)
        pB[ni] = B + (size_t)(bn + ni * 16 + lr) * IN_SIZE + kb + kg;

    f32x4 acc[2][2] = {};
#pragma unroll 4
    for (int k0 = 0; k0 < IN_SIZE / 4; k0 += 32) {
        s16x8 a[2], b[2];
#pragma unroll
        for (int mi = 0; mi < 2; ++mi) { a[mi] = *reinterpret_cast<const s16x8*>(pA[mi]); pA[mi] += 32; }
#pragma unroll
        for (int ni = 0; ni < 2; ++ni) { b[ni] = *reinterpret_cast<const s16x8*>(pB[ni]); pB[ni] += 32; }
#pragma unroll
        for (int mi = 0; mi < 2; ++mi)
#pragma unroll
            for (int ni = 0; ni < 2; ++ni)
                acc[mi][ni] = __builtin_amdgcn_mfma_f32_16x16x32_bf16(a[mi], b[ni], acc[mi][ni], 0, 0, 0);
    }

    float* P = part + (size_t)kz * (BATCH * OUT_SIZE);
#pragma unroll
    for (int mi = 0; mi < 2; ++mi)
#pragma unroll
        for (int ni = 0; ni < 2; ++ni) {
            const int col = bn + ni * 16 + lr;
            const int r0 = bm + w * 32 + mi * 16 + ((l >> 4) << 2);
#pragma unroll
            for (int rr = 0; rr < 4; ++rr)
                P[(size_t)(r0 + rr) * OUT_SIZE + col] = acc[mi][ni][rr];
        }
}

// ---------------------------------------------------------------------------
// K7: Z = relu(sum_kz part + bias)
// ---------------------------------------------------------------------------
__global__ __launch_bounds__(256) void k_reduce(const float* __restrict__ part,
                                               const float* __restrict__ bias,
                                               float* __restrict__ Z) {
    const int i4 = blockIdx.x * 256 + threadIdx.x;   // 0..262143
    const f32x4 p0 = reinterpret_cast<const f32x4*>(part)[i4];
    const f32x4 p1 = reinterpret_cast<const f32x4*>(part + BATCH * OUT_SIZE)[i4];
    const f32x4 p2 = reinterpret_cast<const f32x4*>(part + 2 * BATCH * OUT_SIZE)[i4];
    const f32x4 p3 = reinterpret_cast<const f32x4*>(part + 3 * BATCH * OUT_SIZE)[i4];
    const f32x4 bv = reinterpret_cast<const f32x4*>(bias)[i4 & (OUT_SIZE / 4 - 1)];
    f32x4 o;
#pragma unroll
    for (int k = 0; k < 4; ++k) o[k] = fmaxf(p0[k] + p1[k] + p2[k] + p3[k] + bv[k], 0.f);
    reinterpret_cast<f32x4*>(Z)[i4] = o;
}

// ===========================================================================
// Fallback path (round-2, known-correct) if workspace is too small
// ===========================================================================
#define SC_BLOCKS 1024
__global__ __launch_bounds__(256) void scatter_t(const int2* __restrict__ idx2,
                                                 const float* __restrict__ val,
                                                 float* __restrict__ Wt) {
    const int stride = SC_BLOCKS * 256;
    int i = blockIdx.x * 256 + threadIdx.x;
#pragma unroll 1
    for (int iter = 0; iter < NNZ / (4 * SC_BLOCKS * 256); ++iter) {
        const int2 e0 = idx2[i];
        const int2 e1 = idx2[i + stride];
        const int2 e2 = idx2[i + 2 * stride];
        const int2 e3 = idx2[i + 3 * stride];
        const float v0 = val[i], v1 = val[i + stride], v2 = val[i + 2 * stride], v3 = val[i + 3 * stride];
        atomicAdd(&Wt[e0.y * IN_SIZE + e0.x], v0);
        atomicAdd(&Wt[e1.y * IN_SIZE + e1.x], v1);
        atomicAdd(&Wt[e2.y * IN_SIZE + e2.x], v2);
        atomicAdd(&Wt[e3.y * IN_SIZE + e3.x], v3);
        i += 4 * stride;
    }
}

__global__ __launch_bounds__(256) void gemm_mfma(const float* __restrict__ X,
                                                 const float* __restrict__ Wt,
                                                 const float* __restrict__ bias,
                                                 float* __restrict__ Z) {
    const int l = threadIdx.x & 63, w = threadIdx.x >> 6;
    const int bm = blockIdx.y * 128, bn = blockIdx.x * 32;
    const int lr = l & 15, kg = (l >> 4) * 8;
    const float* pA[2];
    const float* pB[2];
#pragma unroll
    for (int mi = 0; mi < 2; ++mi) pA[mi] = X + (bm + w * 32 + mi * 16 + lr) * IN_SIZE + kg;
#pragma unroll
    for (int ni = 0; ni < 2; ++ni) pB[ni] = Wt + (bn + ni * 16 + lr) * IN_SIZE + kg;
    f32x4 acc[2][2] = {};
#pragma unroll 2
    for (int k0 = 0; k0 < IN_SIZE; k0 += 32) {
        s16x8 a[2], b[2];
#pragma unroll
        for (int mi = 0; mi < 2; ++mi) {
            const f32x4 lo = *reinterpret_cast<const f32x4*>(pA[mi]);
            const f32x4 hi = *reinterpret_cast<const f32x4*>(pA[mi] + 4);
            a[mi] = pack8(lo, hi); pA[mi] += 32;
        }
#pragma unroll
        for (int ni = 0; ni < 2; ++ni) {
            const f32x4 lo = *reinterpret_cast<const f32x4*>(pB[ni]);
            const f32x4 hi = *reinterpret_cast<const f32x4*>(pB[ni] + 4);
            b[ni] = pack8(lo, hi); pB[ni] += 32;
        }
#pragma unroll
        for (int mi = 0; mi < 2; ++mi)
#pragma unroll
            for (int ni = 0; ni < 2; ++ni)
                acc[mi][ni] = __builtin_amdgcn_mfma_f32_16x16x32_bf16(a[mi], b[ni], acc[mi][ni], 0, 0, 0);
    }
#pragma unroll
    for (int mi = 0; mi < 2; ++mi)
#pragma unroll
        for (int ni = 0; ni < 2; ++ni) {
            const int col = bn + ni * 16 + lr;
            const float bv = bias[col];
            const int r0 = bm + w * 32 + mi * 16 + ((l >> 4) << 2);
#pragma unroll
            for (int rr = 0; rr < 4; ++rr)
                Z[(r0 + rr) * OUT_SIZE + col] = fmaxf(acc[mi][ni][rr] + bv, 0.f);
        }
}

extern "C" void kernel_launch(void* const* d_in, const int* in_sizes, int n_in,
                              void* d_out, int out_size, void* d_ws, size_t ws_size,
                              hipStream_t stream) {
    const float* X    = (const float*)d_in[0];
    const int2*  idx2 = (const int2*)d_in[1];
    const float* val  = (const float*)d_in[2];
    const float* bias = (const float*)d_in[3];
    float* Z = (float*)d_out;
    char*  ws = (char*)d_ws;

    if (ws_size >= WS_NEED) {
        s16x8*    Xb     = (s16x8*)(ws + OFF_XBF);
        short*    Wtb    = (short*)(ws + OFF_WTBF);
        float*    part   = (float*)(ws + OFF_PART);
        uint2*    binned = (uint2*)(ws + OFF_BIN);
        unsigned* hist   = (unsigned*)(ws + OFF_HIST);
        unsigned* bpre   = (unsigned*)(ws + OFF_BPRE);
        unsigned* tot    = (unsigned*)(ws + OFF_TOT);
        unsigned* bbase  = (unsigned*)(ws + OFF_BASE);

        k_xcvt<<<(BATCH * IN_SIZE) / (256 * 8), 256, 0, stream>>>(X, Xb);
        k_hist<<<NB, 256, 0, stream>>>(idx2, hist);
        k_scanblocks<<<NB, 256, 0, stream>>>(hist, bpre, tot);
        k_scantot<<<1, 256, 0, stream>>>(tot, bbase);
        k_bin<<<NB, 256, 0, stream>>>(idx2, val, bpre, bbase, binned);
        k_accum<<<NB, 256, 0, stream>>>(binned, bbase, tot, (s16x8*)Wtb);
        dim3 gg(OUT_SIZE / 32, BATCH / 128, 4);
        k_gemm<<<gg, 256, 0, stream>>>((const short*)Xb, Wtb, part);
        k_reduce<<<(BATCH * OUT_SIZE) / (256 * 4), 256, 0, stream>>>(part, bias, Z);
    } else {
        // Fallback: atomic scatter + fused GEMM (round-2 path, needs 64 MB)
        float* Wt = (float*)d_ws;
        hipMemsetAsync(Wt, 0, (size_t)IN_SIZE * OUT_SIZE * sizeof(float), stream);
        scatter_t<<<SC_BLOCKS, 256, 0, stream>>>(idx2, val, Wt);
        dim3 grid(OUT_SIZE / 32, BATCH / 128);
        gemm_mfma<<<grid, 256, 0, stream>>>(X, Wt, bias, Z);
    }
}

// Round 4
// 297.070 us; speedup vs baseline: 2.7974x; 1.1384x over previous
//
#include <hip/hip_runtime.h>
#include <hip/hip_bf16.h>

#define IN_SIZE 4096
#define OUT_SIZE 4096
#define BATCH 256
#define NNZ ((IN_SIZE * OUT_SIZE) / 2)   // 8388608

// Binning: 512 buckets, bucket b = Wt rows [8b, 8b+8)  (Wt = W^T [out][in])
#define NB    512
#define BBIN  512              // binning blocks
#define EPB   (NNZ / BBIN)     // 16384 elements per binning block
#define CHUNK 4096
#define NCH   (EPB / CHUNK)    // 4

typedef float f32x4 __attribute__((ext_vector_type(4)));
typedef short s16x8 __attribute__((ext_vector_type(8)));

// ---- workspace layout (bytes) ----
static const size_t OFF_XBF  = 0;                               // X bf16: 2 MB
static const size_t OFF_WTBF = (size_t)2 << 20;                 // Wt bf16: 32 MB
static const size_t OFF_PART = (size_t)34 << 20;                // 2 partials * 4 MB
static const size_t OFF_BIN  = (size_t)42 << 20;                // packed binned: NNZ*4 = 32 MB
static const size_t OFF_HIST = OFF_BIN + (size_t)NNZ * 4;       // 512*512*4 = 1 MB
static const size_t OFF_BPRE = OFF_HIST + (size_t)BBIN * NB * 4;
static const size_t OFF_TOT  = OFF_BPRE + (size_t)BBIN * NB * 4;
static const size_t OFF_BASE = OFF_TOT + (size_t)NB * 4;
static const size_t WS_NEED  = OFF_BASE + (size_t)NB * 4;       // ~76 MB

__device__ __forceinline__ short bfbits(float f) {
    __hip_bfloat16 h = __float2bfloat16(f);
    return __builtin_bit_cast(short, h);
}
__device__ __forceinline__ s16x8 pack8(f32x4 lo, f32x4 hi) {
    s16x8 r;
    r[0] = bfbits(lo[0]); r[1] = bfbits(lo[1]); r[2] = bfbits(lo[2]); r[3] = bfbits(lo[3]);
    r[4] = bfbits(hi[0]); r[5] = bfbits(hi[1]); r[6] = bfbits(hi[2]); r[7] = bfbits(hi[3]);
    return r;
}
// packed binned element: bits[30:15] = bf16(val) bits, bits[14:0] = pidx
__device__ __forceinline__ unsigned packel(int r, int c, float v) {
    return ((unsigned)(unsigned short)bfbits(v) << 15) |
           (unsigned)((c & 7) * IN_SIZE + r);
}
__device__ __forceinline__ float unpackv(unsigned p) {
    return __uint_as_float((p >> 15) << 16);
}

// Exclusive scan of 512 u32 in LDS h -> out. 256 threads. Returns grand total.
// Trailing __syncthreads() included.
__device__ __forceinline__ unsigned scan512(const unsigned* h, unsigned* out,
                                            unsigned* wsum, int t) {
    const int lane = t & 63, wid = t >> 6;
    const unsigned a0 = h[2 * t], a1 = h[2 * t + 1];
    const unsigned s = a0 + a1;
    unsigned inc = s;
#pragma unroll
    for (int d = 1; d < 64; d <<= 1) {
        const unsigned n = __shfl_up(inc, d);
        if (lane >= d) inc += n;
    }
    if (lane == 63) wsum[wid] = inc;
    __syncthreads();
    unsigned wpre = 0;
#pragma unroll
    for (int i = 0; i < 4; ++i)
        if (i < wid) wpre += wsum[i];
    const unsigned ex = wpre + inc - s;
    out[2 * t]     = ex;
    out[2 * t + 1] = ex + a0;
    const unsigned total = wsum[0] + wsum[1] + wsum[2] + wsum[3];
    __syncthreads();
    return total;
}

// ---------------------------------------------------------------------------
// K0: X fp32 -> bf16
// ---------------------------------------------------------------------------
__global__ __launch_bounds__(256) void k_xcvt(const float* __restrict__ X,
                                              s16x8* __restrict__ Xb) {
    const int i8 = blockIdx.x * 256 + threadIdx.x;
    const f32x4 lo = reinterpret_cast<const f32x4*>(X)[2 * i8];
    const f32x4 hi = reinterpret_cast<const f32x4*>(X)[2 * i8 + 1];
    Xb[i8] = pack8(lo, hi);
}

// ---------------------------------------------------------------------------
// K1: per-block bucket histogram (paired int4 loads: 2 nnz per load)
// ---------------------------------------------------------------------------
__global__ __launch_bounds__(256) void k_hist(const int4* __restrict__ idx4,
                                              unsigned* __restrict__ hist) {
    __shared__ unsigned lh[NB];
    const int t = threadIdx.x, blk = blockIdx.x;
    lh[2 * t] = 0; lh[2 * t + 1] = 0;
    __syncthreads();
    const int pbase = blk * (EPB / 2);
#pragma unroll 8
    for (int j = 0; j < (EPB / 2) / 256; ++j) {   // 32 iters
        const int4 e = idx4[pbase + t + 256 * j];
        atomicAdd(&lh[((unsigned)e.y) >> 3], 1u);
        atomicAdd(&lh[((unsigned)e.w) >> 3], 1u);
    }
    __syncthreads();
    hist[blk * NB + t]       = lh[t];
    hist[blk * NB + t + 256] = lh[t + 256];
}

// ---------------------------------------------------------------------------
// K2: per-bucket exclusive scan over blocks -> bpre[blk][b], totals[b]
// ---------------------------------------------------------------------------
__global__ __launch_bounds__(256) void k_scanblocks(const unsigned* __restrict__ hist,
                                                    unsigned* __restrict__ bpre,
                                                    unsigned* __restrict__ tot) {
    __shared__ unsigned h[BBIN], o[BBIN], wsum[4];
    const int t = threadIdx.x, b = blockIdx.x;
    h[2 * t]     = hist[(2 * t) * NB + b];
    h[2 * t + 1] = hist[(2 * t + 1) * NB + b];
    __syncthreads();
    const unsigned total = scan512(h, o, wsum, t);
    bpre[(2 * t) * NB + b]     = o[2 * t];
    bpre[(2 * t + 1) * NB + b] = o[2 * t + 1];
    if (t == 0) tot[b] = total;
}

// ---------------------------------------------------------------------------
// K3: exclusive scan of bucket totals -> bucket base offsets
// ---------------------------------------------------------------------------
__global__ __launch_bounds__(256) void k_scantot(const unsigned* __restrict__ tot,
                                                 unsigned* __restrict__ bbase) {
    __shared__ unsigned h[NB], o[NB], wsum[4];
    const int t = threadIdx.x;
    h[2 * t] = tot[2 * t]; h[2 * t + 1] = tot[2 * t + 1];
    __syncthreads();
    scan512(h, o, wsum, t);
    bbase[2 * t] = o[2 * t]; bbase[2 * t + 1] = o[2 * t + 1];
}

// ---------------------------------------------------------------------------
// K4: binned scatter with LDS reorder, packed 4B elements.
// LDS: 3*2KB hists + 32KB uint2 staging = ~38KB -> 4 blocks/CU.
// ---------------------------------------------------------------------------
__global__ __launch_bounds__(256) void k_bin(const int4* __restrict__ idx4,
                                             const float2* __restrict__ val2,
                                             const unsigned* __restrict__ bpre,
                                             const unsigned* __restrict__ bbase,
                                             unsigned* __restrict__ binned) {
    __shared__ unsigned cur[NB], hist[NB], start[NB], wsum[4];
    __shared__ uint2 st[CHUNK];        // .x = global dst, .y = packed
    const int t = threadIdx.x, blk = blockIdx.x;
    cur[2 * t]     = bbase[2 * t]     + bpre[blk * NB + 2 * t];
    cur[2 * t + 1] = bbase[2 * t + 1] + bpre[blk * NB + 2 * t + 1];

    for (int ch = 0; ch < NCH; ++ch) {
        hist[2 * t] = 0; hist[2 * t + 1] = 0;
        __syncthreads();
        const int pbase = (blk * EPB + ch * CHUNK) / 2;
        unsigned eb[16], er[16], epk[16];
#pragma unroll
        for (int j = 0; j < 8; ++j) {
            const int4 e   = idx4[pbase + t + 256 * j];
            const float2 v = val2[pbase + t + 256 * j];
            eb[2 * j]      = ((unsigned)e.y) >> 3;
            epk[2 * j]     = packel(e.x, e.y, v.x);
            er[2 * j]      = atomicAdd(&hist[eb[2 * j]], 1u);
            eb[2 * j + 1]  = ((unsigned)e.w) >> 3;
            epk[2 * j + 1] = packel(e.z, e.w, v.y);
            er[2 * j + 1]  = atomicAdd(&hist[eb[2 * j + 1]], 1u);
        }
        __syncthreads();
        scan512(hist, start, wsum, t);   // trailing barrier inside
#pragma unroll
        for (int j = 0; j < 16; ++j) {
            const unsigned lp = start[eb[j]] + er[j];
            st[lp] = make_uint2(cur[eb[j]] + er[j], epk[j]);
        }
        __syncthreads();
        cur[2 * t]     += hist[2 * t];
        cur[2 * t + 1] += hist[2 * t + 1];
#pragma unroll
        for (int j = 0; j < 16; ++j) {
            const uint2 s = st[t + 256 * j];
            binned[s.x] = s.y;
        }
        __syncthreads();
    }
}

// ---------------------------------------------------------------------------
// K5: per-bucket LDS accumulate -> Wt bf16 rows [8b, 8b+8).
// 512 threads (8 waves/CU), 4-deep unrolled gather.
// ---------------------------------------------------------------------------
__global__ __launch_bounds__(512) void k_accum(const unsigned* __restrict__ binned,
                                               const unsigned* __restrict__ bbase,
                                               const unsigned* __restrict__ tot,
                                               s16x8* __restrict__ Wtb8) {
    __shared__ float acc[8 * IN_SIZE];   // 128 KB
    const int t = threadIdx.x, b = blockIdx.x;
    f32x4* a4 = reinterpret_cast<f32x4*>(acc);
#pragma unroll
    for (int j = 0; j < (8 * IN_SIZE / 4) / 512; ++j)
        a4[t + 512 * j] = (f32x4){0.f, 0.f, 0.f, 0.f};
    __syncthreads();
    const unsigned base = bbase[b], n = tot[b];
    const unsigned M = n & ~(unsigned)(4 * 512 - 1);
    for (unsigned i = 4 * t; i < M; i += 4 * 512) {
        const unsigned p0 = binned[base + i];
        const unsigned p1 = binned[base + i + 1];
        const unsigned p2 = binned[base + i + 2];
        const unsigned p3 = binned[base + i + 3];
        atomicAdd(&acc[p0 & 32767u], unpackv(p0));
        atomicAdd(&acc[p1 & 32767u], unpackv(p1));
        atomicAdd(&acc[p2 & 32767u], unpackv(p2));
        atomicAdd(&acc[p3 & 32767u], unpackv(p3));
    }
    for (unsigned j2 = M + t; j2 < n; j2 += 512) {   // tail < 2048
        const unsigned p = binned[base + j2];
        atomicAdd(&acc[p & 32767u], unpackv(p));
    }
    __syncthreads();
    s16x8* dst = Wtb8 + (size_t)b * (8 * IN_SIZE / 8);
#pragma unroll
    for (int j = 0; j < (8 * IN_SIZE / 8) / 512; ++j) {
        const int i8 = t + 512 * j;
        dst[i8] = pack8(a4[2 * i8], a4[2 * i8 + 1]);
    }
}

// ---------------------------------------------------------------------------
// K6: split-K=2 bf16 MFMA GEMM (fragment maps verified rounds 2-3)
// ---------------------------------------------------------------------------
__global__ __launch_bounds__(256) void k_gemm(const short* __restrict__ A,
                                              const short* __restrict__ B,
                                              float* __restrict__ part) {
    const int l = threadIdx.x & 63, w = threadIdx.x >> 6;
    const int bm = blockIdx.y * 128, bn = blockIdx.x * 32, kz = blockIdx.z;
    const int lr = l & 15, kg = (l >> 4) * 8;
    const int kb = kz * (IN_SIZE / 2);

    const short* pA[2];
    const short* pB[2];
#pragma unroll
    for (int mi = 0; mi < 2; ++mi)
        pA[mi] = A + (size_t)(bm + w * 32 + mi * 16 + lr) * IN_SIZE + kb + kg;
#pragma unroll
    for (int ni = 0; ni < 2; ++ni)
        pB[ni] = B + (size_t)(bn + ni * 16 + lr) * IN_SIZE + kb + kg;

    f32x4 acc[2][2] = {};
#pragma unroll 4
    for (int k0 = 0; k0 < IN_SIZE / 2; k0 += 32) {
        s16x8 a[2], b[2];
#pragma unroll
        for (int mi = 0; mi < 2; ++mi) { a[mi] = *reinterpret_cast<const s16x8*>(pA[mi]); pA[mi] += 32; }
#pragma unroll
        for (int ni = 0; ni < 2; ++ni) { b[ni] = *reinterpret_cast<const s16x8*>(pB[ni]); pB[ni] += 32; }
#pragma unroll
        for (int mi = 0; mi < 2; ++mi)
#pragma unroll
            for (int ni = 0; ni < 2; ++ni)
                acc[mi][ni] = __builtin_amdgcn_mfma_f32_16x16x32_bf16(a[mi], b[ni], acc[mi][ni], 0, 0, 0);
    }

    float* P = part + (size_t)kz * (BATCH * OUT_SIZE);
#pragma unroll
    for (int mi = 0; mi < 2; ++mi)
#pragma unroll
        for (int ni = 0; ni < 2; ++ni) {
            const int col = bn + ni * 16 + lr;
            const int r0 = bm + w * 32 + mi * 16 + ((l >> 4) << 2);
#pragma unroll
            for (int rr = 0; rr < 4; ++rr)
                P[(size_t)(r0 + rr) * OUT_SIZE + col] = acc[mi][ni][rr];
        }
}

// ---------------------------------------------------------------------------
// K7: Z = relu(part0 + part1 + bias)
// ---------------------------------------------------------------------------
__global__ __launch_bounds__(256) void k_reduce(const float* __restrict__ part,
                                                const float* __restrict__ bias,
                                                float* __restrict__ Z) {
    const int i4 = blockIdx.x * 256 + threadIdx.x;
    const f32x4 p0 = reinterpret_cast<const f32x4*>(part)[i4];
    const f32x4 p1 = reinterpret_cast<const f32x4*>(part + (size_t)BATCH * OUT_SIZE)[i4];
    const f32x4 bv = reinterpret_cast<const f32x4*>(bias)[i4 & (OUT_SIZE / 4 - 1)];
    f32x4 o;
#pragma unroll
    for (int k = 0; k < 4; ++k) o[k] = fmaxf(p0[k] + p1[k] + bv[k], 0.f);
    reinterpret_cast<f32x4*>(Z)[i4] = o;
}

// ===========================================================================
// Fallback path (round-2, known-correct) if workspace is too small
// ===========================================================================
#define SC_BLOCKS 1024
__global__ __launch_bounds__(256) void scatter_t(const int2* __restrict__ idx2,
                                                 const float* __restrict__ val,
                                                 float* __restrict__ Wt) {
    const int stride = SC_BLOCKS * 256;
    int i = blockIdx.x * 256 + threadIdx.x;
#pragma unroll 1
    for (int iter = 0; iter < NNZ / (4 * SC_BLOCKS * 256); ++iter) {
        const int2 e0 = idx2[i];
        const int2 e1 = idx2[i + stride];
        const int2 e2 = idx2[i + 2 * stride];
        const int2 e3 = idx2[i + 3 * stride];
        const float v0 = val[i], v1 = val[i + stride], v2 = val[i + 2 * stride], v3 = val[i + 3 * stride];
        atomicAdd(&Wt[e0.y * IN_SIZE + e0.x], v0);
        atomicAdd(&Wt[e1.y * IN_SIZE + e1.x], v1);
        atomicAdd(&Wt[e2.y * IN_SIZE + e2.x], v2);
        atomicAdd(&Wt[e3.y * IN_SIZE + e3.x], v3);
        i += 4 * stride;
    }
}

__global__ __launch_bounds__(256) void gemm_mfma(const float* __restrict__ X,
                                                 const float* __restrict__ Wt,
                                                 const float* __restrict__ bias,
                                                 float* __restrict__ Z) {
    const int l = threadIdx.x & 63, w = threadIdx.x >> 6;
    const int bm = blockIdx.y * 128, bn = blockIdx.x * 32;
    const int lr = l & 15, kg = (l >> 4) * 8;
    const float* pA[2];
    const float* pB[2];
#pragma unroll
    for (int mi = 0; mi < 2; ++mi) pA[mi] = X + (bm + w * 32 + mi * 16 + lr) * IN_SIZE + kg;
#pragma unroll
    for (int ni = 0; ni < 2; ++ni) pB[ni] = Wt + (bn + ni * 16 + lr) * IN_SIZE + kg;
    f32x4 acc[2][2] = {};
#pragma unroll 2
    for (int k0 = 0; k0 < IN_SIZE; k0 += 32) {
        s16x8 a[2], b[2];
#pragma unroll
        for (int mi = 0; mi < 2; ++mi) {
            const f32x4 lo = *reinterpret_cast<const f32x4*>(pA[mi]);
            const f32x4 hi = *reinterpret_cast<const f32x4*>(pA[mi] + 4);
            a[mi] = pack8(lo, hi); pA[mi] += 32;
        }
#pragma unroll
        for (int ni = 0; ni < 2; ++ni) {
            const f32x4 lo = *reinterpret_cast<const f32x4*>(pB[ni]);
            const f32x4 hi = *reinterpret_cast<const f32x4*>(pB[ni] + 4);
            b[ni] = pack8(lo, hi); pB[ni] += 32;
        }
#pragma unroll
        for (int mi = 0; mi < 2; ++mi)
#pragma unroll
            for (int ni = 0; ni < 2; ++ni)
                acc[mi][ni] = __builtin_amdgcn_mfma_f32_16x16x32_bf16(a[mi], b[ni], acc[mi][ni], 0, 0, 0);
    }
#pragma unroll
    for (int mi = 0; mi < 2; ++mi)
#pragma unroll
        for (int ni = 0; ni < 2; ++ni) {
            const int col = bn + ni * 16 + lr;
            const float bv = bias[col];
            const int r0 = bm + w * 32 + mi * 16 + ((l >> 4) << 2);
#pragma unroll
            for (int rr = 0; rr < 4; ++rr)
                Z[(r0 + rr) * OUT_SIZE + col] = fmaxf(acc[mi][ni][rr] + bv, 0.f);
        }
}

extern "C" void kernel_launch(void* const* d_in, const int* in_sizes, int n_in,
                              void* d_out, int out_size, void* d_ws, size_t ws_size,
                              hipStream_t stream) {
    const float* X    = (const float*)d_in[0];
    const int*   idx  = (const int*)d_in[1];
    const float* val  = (const float*)d_in[2];
    const float* bias = (const float*)d_in[3];
    float* Z = (float*)d_out;
    char*  ws = (char*)d_ws;

    if (ws_size >= WS_NEED) {
        s16x8*    Xb     = (s16x8*)(ws + OFF_XBF);
        short*    Wtb    = (short*)(ws + OFF_WTBF);
        float*    part   = (float*)(ws + OFF_PART);
        unsigned* binned = (unsigned*)(ws + OFF_BIN);
        unsigned* hist   = (unsigned*)(ws + OFF_HIST);
        unsigned* bpre   = (unsigned*)(ws + OFF_BPRE);
        unsigned* tot    = (unsigned*)(ws + OFF_TOT);
        unsigned* bbase  = (unsigned*)(ws + OFF_BASE);

        k_xcvt<<<(BATCH * IN_SIZE) / (256 * 8), 256, 0, stream>>>(X, Xb);
        k_hist<<<BBIN, 256, 0, stream>>>((const int4*)idx, hist);
        k_scanblocks<<<NB, 256, 0, stream>>>(hist, bpre, tot);
        k_scantot<<<1, 256, 0, stream>>>(tot, bbase);
        k_bin<<<BBIN, 256, 0, stream>>>((const int4*)idx, (const float2*)val, bpre, bbase, binned);
        k_accum<<<NB, 512, 0, stream>>>(binned, bbase, tot, (s16x8*)Wtb);
        dim3 gg(OUT_SIZE / 32, BATCH / 128, 2);
        k_gemm<<<gg, 256, 0, stream>>>((const short*)Xb, Wtb, part);
        k_reduce<<<(BATCH * OUT_SIZE) / (256 * 4), 256, 0, stream>>>(part, bias, Z);
    } else {
        float* Wt = (float*)d_ws;
        hipMemsetAsync(Wt, 0, (size_t)IN_SIZE * OUT_SIZE * sizeof(float), stream);
        scatter_t<<<SC_BLOCKS, 256, 0, stream>>>((const int2*)idx, val, Wt);
        dim3 grid(OUT_SIZE / 32, BATCH / 128);
        gemm_mfma<<<grid, 256, 0, stream>>>(X, Wt, bias, Z);
    }
}

// Round 5
// 273.370 us; speedup vs baseline: 3.0399x; 1.0867x over previous
//
#include <hip/hip_runtime.h>
#include <hip/hip_bf16.h>

#define IN_SIZE 4096
#define OUT_SIZE 4096
#define BATCH 256
#define NNZ ((IN_SIZE * OUT_SIZE) / 2)   // 8388608

// Binning: 512 buckets, bucket b = Wt rows [8b, 8b+8)  (Wt = W^T [out][in])
#define NB    512
#define BBIN  512              // binning blocks
#define EPB   (NNZ / BBIN)     // 16384 elements per binning block
#define CHUNK 4096
#define NCH   (EPB / CHUNK)    // 4
#define REP    8               // counter replicas (blk & 7)
#define SUBCAP 3072            // per-replica sub-region (mean 2048, +22 sigma)
#define CAP    (REP * SUBCAP)  // 24576 slots per bucket
#define SPLITK 8

typedef float f32x4 __attribute__((ext_vector_type(4)));
typedef short s16x8 __attribute__((ext_vector_type(8)));

// ---- workspace layout (bytes) ----
static const size_t OFF_XBF  = 0;                               // X bf16: 2 MB
static const size_t OFF_WTBF = (size_t)2 << 20;                 // Wt bf16: 32 MB
static const size_t OFF_PART = (size_t)34 << 20;                // 8 partials * 4 MB = 32 MB
static const size_t OFF_BIN  = (size_t)66 << 20;                // binned: 512*24576*4 = 48 MB
static const size_t OFF_CNT  = (size_t)114 << 20;               // counters: 8*512*4 = 16 KB
static const size_t WS_NEED  = OFF_CNT + (size_t)REP * NB * 4;  // ~114 MB

__device__ __forceinline__ short bfbits(float f) {
    __hip_bfloat16 h = __float2bfloat16(f);
    return __builtin_bit_cast(short, h);
}
__device__ __forceinline__ s16x8 pack8(f32x4 lo, f32x4 hi) {
    s16x8 r;
    r[0] = bfbits(lo[0]); r[1] = bfbits(lo[1]); r[2] = bfbits(lo[2]); r[3] = bfbits(lo[3]);
    r[4] = bfbits(hi[0]); r[5] = bfbits(hi[1]); r[6] = bfbits(hi[2]); r[7] = bfbits(hi[3]);
    return r;
}
// packed binned element: bits[30:15] = bf16(val) bits, bits[14:0] = pidx
__device__ __forceinline__ unsigned packel(int r, int c, float v) {
    return ((unsigned)(unsigned short)bfbits(v) << 15) |
           (unsigned)((c & 7) * IN_SIZE + r);
}
__device__ __forceinline__ float unpackv(unsigned p) {
    return __uint_as_float((p >> 15) << 16);
}

// Exclusive scan of 512 u32 in LDS h -> out. 256 threads. Trailing barrier.
__device__ __forceinline__ void scan512(const unsigned* h, unsigned* out,
                                        unsigned* wsum, int t) {
    const int lane = t & 63, wid = t >> 6;
    const unsigned a0 = h[2 * t], a1 = h[2 * t + 1];
    const unsigned s = a0 + a1;
    unsigned inc = s;
#pragma unroll
    for (int d = 1; d < 64; d <<= 1) {
        const unsigned n = __shfl_up(inc, d);
        if (lane >= d) inc += n;
    }
    if (lane == 63) wsum[wid] = inc;
    __syncthreads();
    unsigned wpre = 0;
#pragma unroll
    for (int i = 0; i < 4; ++i)
        if (i < wid) wpre += wsum[i];
    const unsigned ex = wpre + inc - s;
    out[2 * t]     = ex;
    out[2 * t + 1] = ex + a0;
    __syncthreads();
}

// ---------------------------------------------------------------------------
// K0: X fp32 -> bf16
// ---------------------------------------------------------------------------
__global__ __launch_bounds__(256) void k_xcvt(const float* __restrict__ X,
                                              s16x8* __restrict__ Xb) {
    const int i8 = blockIdx.x * 256 + threadIdx.x;
    const f32x4 lo = reinterpret_cast<const f32x4*>(X)[2 * i8];
    const f32x4 hi = reinterpret_cast<const f32x4*>(X)[2 * i8 + 1];
    Xb[i8] = pack8(lo, hi);
}

// ---------------------------------------------------------------------------
// K1: fused binning: LDS hist + scan + global atomic reserve + LDS reorder.
// Replaces the old k_hist / k_scanblocks / k_scantot / k_bin chain.
// cnt layout: cnt[rep][b]; bucket region: b*CAP + rep*SUBCAP + offset.
// ---------------------------------------------------------------------------
__global__ __launch_bounds__(256) void k_bin(const int4* __restrict__ idx4,
                                             const float2* __restrict__ val2,
                                             unsigned* __restrict__ cnt,
                                             unsigned* __restrict__ binned) {
    __shared__ unsigned hist[NB], start[NB], curb[NB], wsum[4];
    __shared__ uint2 st[CHUNK];        // .x = global dst, .y = packed
    const int t = threadIdx.x, blk = blockIdx.x;
    const int rep = blk & (REP - 1);

    for (int ch = 0; ch < NCH; ++ch) {
        hist[2 * t] = 0; hist[2 * t + 1] = 0;
        __syncthreads();
        const int pbase = (blk * EPB + ch * CHUNK) / 2;
        unsigned eb[16], er[16], epk[16];
#pragma unroll
        for (int j = 0; j < 8; ++j) {
            const int4 e   = idx4[pbase + t + 256 * j];
            const float2 v = val2[pbase + t + 256 * j];
            eb[2 * j]      = ((unsigned)e.y) >> 3;
            epk[2 * j]     = packel(e.x, e.y, v.x);
            er[2 * j]      = atomicAdd(&hist[eb[2 * j]], 1u);
            eb[2 * j + 1]  = ((unsigned)e.w) >> 3;
            epk[2 * j + 1] = packel(e.z, e.w, v.y);
            er[2 * j + 1]  = atomicAdd(&hist[eb[2 * j + 1]], 1u);
        }
        __syncthreads();
        scan512(hist, start, wsum, t);   // trailing barrier inside
        // reserve space for this chunk's elements (thread t owns buckets 2t, 2t+1)
        {
            const unsigned h0 = hist[2 * t], h1 = hist[2 * t + 1];
            const unsigned r0 = h0 ? atomicAdd(&cnt[rep * NB + 2 * t], h0) : 0u;
            const unsigned r1 = h1 ? atomicAdd(&cnt[rep * NB + 2 * t + 1], h1) : 0u;
            curb[2 * t]     = (unsigned)(2 * t) * CAP + rep * SUBCAP + r0;
            curb[2 * t + 1] = (unsigned)(2 * t + 1) * CAP + rep * SUBCAP + r1;
        }
        __syncthreads();
#pragma unroll
        for (int j = 0; j < 16; ++j) {
            const unsigned lp = start[eb[j]] + er[j];
            st[lp] = make_uint2(curb[eb[j]] + er[j], epk[j]);
        }
        __syncthreads();
#pragma unroll
        for (int j = 0; j < 16; ++j) {
            const uint2 s = st[t + 256 * j];
            binned[s.x] = s.y;
        }
        __syncthreads();
    }
}

// ---------------------------------------------------------------------------
// K2: per-bucket LDS accumulate -> Wt bf16 rows [8b, 8b+8). 1024 threads.
// ---------------------------------------------------------------------------
__global__ __launch_bounds__(1024) void k_accum(const unsigned* __restrict__ binned,
                                                const unsigned* __restrict__ cnt,
                                                s16x8* __restrict__ Wtb8) {
    __shared__ float acc[8 * IN_SIZE];   // 128 KB
    const int t = threadIdx.x, b = blockIdx.x;
    f32x4* a4 = reinterpret_cast<f32x4*>(acc);
#pragma unroll
    for (int j = 0; j < (8 * IN_SIZE / 4) / 1024; ++j)
        a4[t + 1024 * j] = (f32x4){0.f, 0.f, 0.f, 0.f};
    __syncthreads();
    const unsigned base = (unsigned)b * CAP;
#pragma unroll 1
    for (int r = 0; r < REP; ++r) {
        const unsigned n  = cnt[r * NB + b];
        const unsigned rb = base + r * SUBCAP;
        for (unsigned i = t; i < n; i += 1024) {
            const unsigned p = binned[rb + i];
            atomicAdd(&acc[p & 32767u], unpackv(p));
        }
    }
    __syncthreads();
    s16x8* dst = Wtb8 + (size_t)b * (8 * IN_SIZE / 8);
#pragma unroll
    for (int j = 0; j < (8 * IN_SIZE / 8) / 1024; ++j) {
        const int i8 = t + 1024 * j;
        dst[i8] = pack8(a4[2 * i8], a4[2 * i8 + 1]);
    }
}

// ---------------------------------------------------------------------------
// K3: split-K=8 bf16 MFMA GEMM, one-deep software pipeline.
// Fragment maps verified rounds 2-4.
// ---------------------------------------------------------------------------
__global__ __launch_bounds__(256) void k_gemm(const short* __restrict__ A,
                                              const short* __restrict__ B,
                                              float* __restrict__ part) {
    const int l = threadIdx.x & 63, w = threadIdx.x >> 6;
    const int bm = blockIdx.y * 128, bn = blockIdx.x * 32, kz = blockIdx.z;
    const int lr = l & 15, kg = (l >> 4) * 8;
    const int kb = kz * (IN_SIZE / SPLITK);          // 512-wide K slice

    const short* pA[2];
    const short* pB[2];
#pragma unroll
    for (int mi = 0; mi < 2; ++mi)
        pA[mi] = A + (size_t)(bm + w * 32 + mi * 16 + lr) * IN_SIZE + kb + kg;
#pragma unroll
    for (int ni = 0; ni < 2; ++ni)
        pB[ni] = B + (size_t)(bn + ni * 16 + lr) * IN_SIZE + kb + kg;

    f32x4 acc[2][2] = {};
    s16x8 a[2], b[2];
#pragma unroll
    for (int mi = 0; mi < 2; ++mi) { a[mi] = *reinterpret_cast<const s16x8*>(pA[mi]); pA[mi] += 32; }
#pragma unroll
    for (int ni = 0; ni < 2; ++ni) { b[ni] = *reinterpret_cast<const s16x8*>(pB[ni]); pB[ni] += 32; }

#pragma unroll 2
    for (int s = 0; s < (IN_SIZE / SPLITK) / 32 - 1; ++s) {
        s16x8 na[2], nb[2];
#pragma unroll
        for (int mi = 0; mi < 2; ++mi) { na[mi] = *reinterpret_cast<const s16x8*>(pA[mi]); pA[mi] += 32; }
#pragma unroll
        for (int ni = 0; ni < 2; ++ni) { nb[ni] = *reinterpret_cast<const s16x8*>(pB[ni]); pB[ni] += 32; }
#pragma unroll
        for (int mi = 0; mi < 2; ++mi)
#pragma unroll
            for (int ni = 0; ni < 2; ++ni)
                acc[mi][ni] = __builtin_amdgcn_mfma_f32_16x16x32_bf16(a[mi], b[ni], acc[mi][ni], 0, 0, 0);
#pragma unroll
        for (int mi = 0; mi < 2; ++mi) a[mi] = na[mi];
#pragma unroll
        for (int ni = 0; ni < 2; ++ni) b[ni] = nb[ni];
    }
#pragma unroll
    for (int mi = 0; mi < 2; ++mi)
#pragma unroll
        for (int ni = 0; ni < 2; ++ni)
            acc[mi][ni] = __builtin_amdgcn_mfma_f32_16x16x32_bf16(a[mi], b[ni], acc[mi][ni], 0, 0, 0);

    float* P = part + (size_t)kz * (BATCH * OUT_SIZE);
#pragma unroll
    for (int mi = 0; mi < 2; ++mi)
#pragma unroll
        for (int ni = 0; ni < 2; ++ni) {
            const int col = bn + ni * 16 + lr;
            const int r0 = bm + w * 32 + mi * 16 + ((l >> 4) << 2);
#pragma unroll
            for (int rr = 0; rr < 4; ++rr)
                P[(size_t)(r0 + rr) * OUT_SIZE + col] = acc[mi][ni][rr];
        }
}

// ---------------------------------------------------------------------------
// K4: Z = relu(sum of 8 partials + bias)
// ---------------------------------------------------------------------------
__global__ __launch_bounds__(256) void k_reduce(const float* __restrict__ part,
                                                const float* __restrict__ bias,
                                                float* __restrict__ Z) {
    const int i4 = blockIdx.x * 256 + threadIdx.x;
    f32x4 s = reinterpret_cast<const f32x4*>(part)[i4];
#pragma unroll
    for (int r = 1; r < SPLITK; ++r) {
        const f32x4 p = reinterpret_cast<const f32x4*>(part + (size_t)r * BATCH * OUT_SIZE)[i4];
#pragma unroll
        for (int k = 0; k < 4; ++k) s[k] += p[k];
    }
    const f32x4 bv = reinterpret_cast<const f32x4*>(bias)[i4 & (OUT_SIZE / 4 - 1)];
    f32x4 o;
#pragma unroll
    for (int k = 0; k < 4; ++k) o[k] = fmaxf(s[k] + bv[k], 0.f);
    reinterpret_cast<f32x4*>(Z)[i4] = o;
}

// ===========================================================================
// Fallback path (round-2, known-correct) if workspace is too small
// ===========================================================================
#define SC_BLOCKS 1024
__global__ __launch_bounds__(256) void scatter_t(const int2* __restrict__ idx2,
                                                 const float* __restrict__ val,
                                                 float* __restrict__ Wt) {
    const int stride = SC_BLOCKS * 256;
    int i = blockIdx.x * 256 + threadIdx.x;
#pragma unroll 1
    for (int iter = 0; iter < NNZ / (4 * SC_BLOCKS * 256); ++iter) {
        const int2 e0 = idx2[i];
        const int2 e1 = idx2[i + stride];
        const int2 e2 = idx2[i + 2 * stride];
        const int2 e3 = idx2[i + 3 * stride];
        const float v0 = val[i], v1 = val[i + stride], v2 = val[i + 2 * stride], v3 = val[i + 3 * stride];
        atomicAdd(&Wt[e0.y * IN_SIZE + e0.x], v0);
        atomicAdd(&Wt[e1.y * IN_SIZE + e1.x], v1);
        atomicAdd(&Wt[e2.y * IN_SIZE + e2.x], v2);
        atomicAdd(&Wt[e3.y * IN_SIZE + e3.x], v3);
        i += 4 * stride;
    }
}

__global__ __launch_bounds__(256) void gemm_mfma(const float* __restrict__ X,
                                                 const float* __restrict__ Wt,
                                                 const float* __restrict__ bias,
                                                 float* __restrict__ Z) {
    const int l = threadIdx.x & 63, w = threadIdx.x >> 6;
    const int bm = blockIdx.y * 128, bn = blockIdx.x * 32;
    const int lr = l & 15, kg = (l >> 4) * 8;
    const float* pA[2];
    const float* pB[2];
#pragma unroll
    for (int mi = 0; mi < 2; ++mi) pA[mi] = X + (bm + w * 32 + mi * 16 + lr) * IN_SIZE + kg;
#pragma unroll
    for (int ni = 0; ni < 2; ++ni) pB[ni] = Wt + (bn + ni * 16 + lr) * IN_SIZE + kg;
    f32x4 acc[2][2] = {};
#pragma unroll 2
    for (int k0 = 0; k0 < IN_SIZE; k0 += 32) {
        s16x8 a[2], b[2];
#pragma unroll
        for (int mi = 0; mi < 2; ++mi) {
            const f32x4 lo = *reinterpret_cast<const f32x4*>(pA[mi]);
            const f32x4 hi = *reinterpret_cast<const f32x4*>(pA[mi] + 4);
            a[mi] = pack8(lo, hi); pA[mi] += 32;
        }
#pragma unroll
        for (int ni = 0; ni < 2; ++ni) {
            const f32x4 lo = *reinterpret_cast<const f32x4*>(pB[ni]);
            const f32x4 hi = *reinterpret_cast<const f32x4*>(pB[ni] + 4);
            b[ni] = pack8(lo, hi); pB[ni] += 32;
        }
#pragma unroll
        for (int mi = 0; mi < 2; ++mi)
#pragma unroll
            for (int ni = 0; ni < 2; ++ni)
                acc[mi][ni] = __builtin_amdgcn_mfma_f32_16x16x32_bf16(a[mi], b[ni], acc[mi][ni], 0, 0, 0);
    }
#pragma unroll
    for (int mi = 0; mi < 2; ++mi)
#pragma unroll
        for (int ni = 0; ni < 2; ++ni) {
            const int col = bn + ni * 16 + lr;
            const float bv = bias[col];
            const int r0 = bm + w * 32 + mi * 16 + ((l >> 4) << 2);
#pragma unroll
            for (int rr = 0; rr < 4; ++rr)
                Z[(r0 + rr) * OUT_SIZE + col] = fmaxf(acc[mi][ni][rr] + bv, 0.f);
        }
}

extern "C" void kernel_launch(void* const* d_in, const int* in_sizes, int n_in,
                              void* d_out, int out_size, void* d_ws, size_t ws_size,
                              hipStream_t stream) {
    const float* X    = (const float*)d_in[0];
    const int*   idx  = (const int*)d_in[1];
    const float* val  = (const float*)d_in[2];
    const float* bias = (const float*)d_in[3];
    float* Z = (float*)d_out;
    char*  ws = (char*)d_ws;

    if (ws_size >= WS_NEED) {
        s16x8*    Xb     = (s16x8*)(ws + OFF_XBF);
        short*    Wtb    = (short*)(ws + OFF_WTBF);
        float*    part   = (float*)(ws + OFF_PART);
        unsigned* binned = (unsigned*)(ws + OFF_BIN);
        unsigned* cnt    = (unsigned*)(ws + OFF_CNT);

        hipMemsetAsync(cnt, 0, (size_t)REP * NB * 4, stream);
        k_xcvt<<<(BATCH * IN_SIZE) / (256 * 8), 256, 0, stream>>>(X, Xb);
        k_bin<<<BBIN, 256, 0, stream>>>((const int4*)idx, (const float2*)val, cnt, binned);
        k_accum<<<NB, 1024, 0, stream>>>(binned, cnt, (s16x8*)Wtb);
        dim3 gg(OUT_SIZE / 32, BATCH / 128, SPLITK);
        k_gemm<<<gg, 256, 0, stream>>>((const short*)Xb, Wtb, part);
        k_reduce<<<(BATCH * OUT_SIZE) / (256 * 4), 256, 0, stream>>>(part, bias, Z);
    } else {
        float* Wt = (float*)d_ws;
        hipMemsetAsync(Wt, 0, (size_t)IN_SIZE * OUT_SIZE * sizeof(float), stream);
        scatter_t<<<SC_BLOCKS, 256, 0, stream>>>((const int2*)idx, val, Wt);
        dim3 grid(OUT_SIZE / 32, BATCH / 128);
        gemm_mfma<<<grid, 256, 0, stream>>>(X, Wt, bias, Z);
    }
}

// Round 6
// 227.338 us; speedup vs baseline: 3.6554x; 1.2025x over previous
//
#include <hip/hip_runtime.h>
#include <hip/hip_bf16.h>

#define IN_SIZE 4096
#define OUT_SIZE 4096
#define BATCH 256
#define NNZ ((IN_SIZE * OUT_SIZE) / 2)   // 8388608

// Binning: 512 buckets, bucket b = Wt rows [8b, 8b+8)  (Wt = W^T [out][in])
#define NB    512
#define BBIN  1024             // binning blocks (4 blocks/CU)
#define EPB   (NNZ / BBIN)     // 8192 elements per binning block
#define CHUNK 4096
#define NCH   (EPB / CHUNK)    // 2
#define REP    8               // counter replicas (blk & 7)
#define SUBCAP 3072            // per-replica sub-region (mean 2048, +22 sigma)
#define CAP    (REP * SUBCAP)  // 24576 slots per bucket
#define SPLITK 4

// GEMM tile
#define BM 64
#define BN 64
#define BK 64
#define LDA 72                 // padded LDS row stride (shorts): conflict-free

typedef float f32x4 __attribute__((ext_vector_type(4)));
typedef short s16x8 __attribute__((ext_vector_type(8)));

// ---- workspace layout (bytes) ----
static const size_t OFF_XBF  = 0;                               // X bf16: 2 MB
static const size_t OFF_WTBF = (size_t)2 << 20;                 // Wt bf16: 32 MB
static const size_t OFF_PART = (size_t)34 << 20;                // 4 partials * 4 MB = 16 MB
static const size_t OFF_BIN  = (size_t)50 << 20;                // binned: 512*24576*4 = 48 MB
static const size_t OFF_CNT  = (size_t)98 << 20;                // counters: 8*512*4 = 16 KB
static const size_t WS_NEED  = OFF_CNT + (size_t)REP * NB * 4;  // ~98 MB

__device__ __forceinline__ short bfbits(float f) {
    __hip_bfloat16 h = __float2bfloat16(f);
    return __builtin_bit_cast(short, h);
}
__device__ __forceinline__ s16x8 pack8(f32x4 lo, f32x4 hi) {
    s16x8 r;
    r[0] = bfbits(lo[0]); r[1] = bfbits(lo[1]); r[2] = bfbits(lo[2]); r[3] = bfbits(lo[3]);
    r[4] = bfbits(hi[0]); r[5] = bfbits(hi[1]); r[6] = bfbits(hi[2]); r[7] = bfbits(hi[3]);
    return r;
}
// packed binned element: bits[30:15] = bf16(val) bits, bits[14:0] = pidx
__device__ __forceinline__ unsigned packel(int r, int c, float v) {
    return ((unsigned)(unsigned short)bfbits(v) << 15) |
           (unsigned)((c & 7) * IN_SIZE + r);
}
__device__ __forceinline__ float unpackv(unsigned p) {
    return __uint_as_float((p >> 15) << 16);
}

// Exclusive scan of 512 u32 in LDS h -> out. 256 threads. Trailing barrier.
__device__ __forceinline__ void scan512(const unsigned* h, unsigned* out,
                                        unsigned* wsum, int t) {
    const int lane = t & 63, wid = t >> 6;
    const unsigned a0 = h[2 * t], a1 = h[2 * t + 1];
    const unsigned s = a0 + a1;
    unsigned inc = s;
#pragma unroll
    for (int d = 1; d < 64; d <<= 1) {
        const unsigned n = __shfl_up(inc, d);
        if (lane >= d) inc += n;
    }
    if (lane == 63) wsum[wid] = inc;
    __syncthreads();
    unsigned wpre = 0;
#pragma unroll
    for (int i = 0; i < 4; ++i)
        if (i < wid) wpre += wsum[i];
    const unsigned ex = wpre + inc - s;
    out[2 * t]     = ex;
    out[2 * t + 1] = ex + a0;
    __syncthreads();
}

// ---------------------------------------------------------------------------
// K0: X fp32 -> bf16
// ---------------------------------------------------------------------------
__global__ __launch_bounds__(256) void k_xcvt(const float* __restrict__ X,
                                              s16x8* __restrict__ Xb) {
    const int i8 = blockIdx.x * 256 + threadIdx.x;
    const f32x4 lo = reinterpret_cast<const f32x4*>(X)[2 * i8];
    const f32x4 hi = reinterpret_cast<const f32x4*>(X)[2 * i8 + 1];
    Xb[i8] = pack8(lo, hi);
}

// ---------------------------------------------------------------------------
// K1: fused binning: LDS hist + scan + global atomic reserve + LDS reorder.
// cnt layout: cnt[rep][b]; bucket region: b*CAP + rep*SUBCAP + offset.
// ---------------------------------------------------------------------------
__global__ __launch_bounds__(256) void k_bin(const int4* __restrict__ idx4,
                                             const float2* __restrict__ val2,
                                             unsigned* __restrict__ cnt,
                                             unsigned* __restrict__ binned) {
    __shared__ unsigned hist[NB], start[NB], curb[NB], wsum[4];
    __shared__ uint2 st[CHUNK];        // .x = global dst, .y = packed
    const int t = threadIdx.x, blk = blockIdx.x;
    const int rep = blk & (REP - 1);

    for (int ch = 0; ch < NCH; ++ch) {
        hist[2 * t] = 0; hist[2 * t + 1] = 0;
        __syncthreads();
        const int pbase = (blk * EPB + ch * CHUNK) / 2;
        unsigned eb[16], er[16], epk[16];
#pragma unroll
        for (int j = 0; j < 8; ++j) {
            const int4 e   = idx4[pbase + t + 256 * j];
            const float2 v = val2[pbase + t + 256 * j];
            eb[2 * j]      = ((unsigned)e.y) >> 3;
            epk[2 * j]     = packel(e.x, e.y, v.x);
            er[2 * j]      = atomicAdd(&hist[eb[2 * j]], 1u);
            eb[2 * j + 1]  = ((unsigned)e.w) >> 3;
            epk[2 * j + 1] = packel(e.z, e.w, v.y);
            er[2 * j + 1]  = atomicAdd(&hist[eb[2 * j + 1]], 1u);
        }
        __syncthreads();
        scan512(hist, start, wsum, t);   // trailing barrier inside
        // reserve space for this chunk (thread t owns buckets 2t, 2t+1)
        {
            const unsigned h0 = hist[2 * t], h1 = hist[2 * t + 1];
            const unsigned r0 = h0 ? atomicAdd(&cnt[rep * NB + 2 * t], h0) : 0u;
            const unsigned r1 = h1 ? atomicAdd(&cnt[rep * NB + 2 * t + 1], h1) : 0u;
            curb[2 * t]     = (unsigned)(2 * t) * CAP + rep * SUBCAP + r0;
            curb[2 * t + 1] = (unsigned)(2 * t + 1) * CAP + rep * SUBCAP + r1;
        }
        __syncthreads();
#pragma unroll
        for (int j = 0; j < 16; ++j) {
            const unsigned lp = start[eb[j]] + er[j];
            st[lp] = make_uint2(curb[eb[j]] + er[j], epk[j]);
        }
        __syncthreads();
#pragma unroll
        for (int j = 0; j < 16; ++j) {
            const uint2 s = st[t + 256 * j];
            binned[s.x] = s.y;
        }
        __syncthreads();
    }
}

// ---------------------------------------------------------------------------
// K2: per-bucket LDS accumulate -> Wt bf16 rows [8b, 8b+8). 1024 threads.
// ---------------------------------------------------------------------------
__global__ __launch_bounds__(1024) void k_accum(const unsigned* __restrict__ binned,
                                                const unsigned* __restrict__ cnt,
                                                s16x8* __restrict__ Wtb8) {
    __shared__ float acc[8 * IN_SIZE];   // 128 KB
    const int t = threadIdx.x, b = blockIdx.x;
    f32x4* a4 = reinterpret_cast<f32x4*>(acc);
#pragma unroll
    for (int j = 0; j < (8 * IN_SIZE / 4) / 1024; ++j)
        a4[t + 1024 * j] = (f32x4){0.f, 0.f, 0.f, 0.f};
    __syncthreads();
    const unsigned base = (unsigned)b * CAP;
#pragma unroll 1
    for (int r = 0; r < REP; ++r) {
        const unsigned n  = cnt[r * NB + b];
        const unsigned rb = base + r * SUBCAP;
        for (unsigned i = t; i < n; i += 1024) {
            const unsigned p = binned[rb + i];
            atomicAdd(&acc[p & 32767u], unpackv(p));
        }
    }
    __syncthreads();
    s16x8* dst = Wtb8 + (size_t)b * (8 * IN_SIZE / 8);
#pragma unroll
    for (int j = 0; j < (8 * IN_SIZE / 8) / 1024; ++j) {
        const int i8 = t + 1024 * j;
        dst[i8] = pack8(a4[2 * i8], a4[2 * i8 + 1]);
    }
}

// ---------------------------------------------------------------------------
// K3: LDS-staged bf16 MFMA GEMM. 64x64 tile, BK=64, 4 waves (each 32x32),
// split-K=4, reg-staged global->LDS with padded rows (LDA=72, conflict-free).
// Prefetch next tile AFTER 2nd barrier so latency hides under ds_read+MFMA.
// Fragment maps verified rounds 2-5:
//   A: lane l holds A[l&15][kg+j]; B: lane holds B[kg+j][l&15];
//   D: reg rr -> row (l>>4)*4+rr, col l&15
// ---------------------------------------------------------------------------
__global__ __launch_bounds__(256) void k_gemm(const short* __restrict__ A,
                                              const short* __restrict__ B,
                                              float* __restrict__ part) {
    __shared__ short As[BM * LDA];   // 9216 shorts = 18 KB
    __shared__ short Bs[BN * LDA];   // 18 KB
    const int t  = threadIdx.x;
    const int l  = t & 63;
    const int w  = t >> 6;
    const int wm = (w >> 1) * 32, wn = (w & 1) * 32;   // wave's 32x32 sub-tile
    const int lr = l & 15, kg = (l >> 4) * 8;
    const int bn = blockIdx.x * BN, bm = blockIdx.y * BM;
    const size_t kb = (size_t)blockIdx.z * (IN_SIZE / SPLITK);

    // staging: unit s = t + 256*phase; row = s>>3 (0..63), c16 = s&7
    const int r0s = t >> 3;            // rows 0..31 (phase 0)
    const int r1s = r0s + 32;          // rows 32..63 (phase 1)
    const int c0  = (t & 7) * 8;       // short offset within row
    const short* gA0 = A + (size_t)(bm + r0s) * IN_SIZE + kb + c0;
    const short* gA1 = A + (size_t)(bm + r1s) * IN_SIZE + kb + c0;
    const short* gB0 = B + (size_t)(bn + r0s) * IN_SIZE + kb + c0;
    const short* gB1 = B + (size_t)(bn + r1s) * IN_SIZE + kb + c0;

    f32x4 acc[2][2] = {};
    s16x8 ra0 = *reinterpret_cast<const s16x8*>(gA0);
    s16x8 ra1 = *reinterpret_cast<const s16x8*>(gA1);
    s16x8 rb0 = *reinterpret_cast<const s16x8*>(gB0);
    s16x8 rb1 = *reinterpret_cast<const s16x8*>(gB1);

    const int NIT = (IN_SIZE / SPLITK) / BK;   // 16
#pragma unroll 1
    for (int it = 0; it < NIT; ++it) {
        __syncthreads();   // previous iter's ds_reads complete
        *reinterpret_cast<s16x8*>(&As[r0s * LDA + c0]) = ra0;
        *reinterpret_cast<s16x8*>(&As[r1s * LDA + c0]) = ra1;
        *reinterpret_cast<s16x8*>(&Bs[r0s * LDA + c0]) = rb0;
        *reinterpret_cast<s16x8*>(&Bs[r1s * LDA + c0]) = rb1;
        __syncthreads();   // tile visible (drains vmcnt here, right before reuse)
        if (it + 1 < NIT) {
            const int o = (it + 1) * BK;
            ra0 = *reinterpret_cast<const s16x8*>(gA0 + o);
            ra1 = *reinterpret_cast<const s16x8*>(gA1 + o);
            rb0 = *reinterpret_cast<const s16x8*>(gB0 + o);
            rb1 = *reinterpret_cast<const s16x8*>(gB1 + o);
        }
        s16x8 af[2][2], bf[2][2];
#pragma unroll
        for (int kk = 0; kk < 2; ++kk) {
#pragma unroll
            for (int mi = 0; mi < 2; ++mi)
                af[kk][mi] = *reinterpret_cast<const s16x8*>(
                    &As[(wm + mi * 16 + lr) * LDA + kk * 32 + kg]);
#pragma unroll
            for (int ni = 0; ni < 2; ++ni)
                bf[kk][ni] = *reinterpret_cast<const s16x8*>(
                    &Bs[(wn + ni * 16 + lr) * LDA + kk * 32 + kg]);
        }
#pragma unroll
        for (int kk = 0; kk < 2; ++kk)
#pragma unroll
            for (int mi = 0; mi < 2; ++mi)
#pragma unroll
                for (int ni = 0; ni < 2; ++ni)
                    acc[mi][ni] = __builtin_amdgcn_mfma_f32_16x16x32_bf16(
                        af[kk][mi], bf[kk][ni], acc[mi][ni], 0, 0, 0);
    }

    float* P = part + (size_t)blockIdx.z * (BATCH * OUT_SIZE);
#pragma unroll
    for (int mi = 0; mi < 2; ++mi)
#pragma unroll
        for (int ni = 0; ni < 2; ++ni) {
            const int col = bn + wn + ni * 16 + lr;
            const int r0 = bm + wm + mi * 16 + ((l >> 4) << 2);
#pragma unroll
            for (int rr = 0; rr < 4; ++rr)
                P[(size_t)(r0 + rr) * OUT_SIZE + col] = acc[mi][ni][rr];
        }
}

// ---------------------------------------------------------------------------
// K4: Z = relu(sum of 4 partials + bias)
// ---------------------------------------------------------------------------
__global__ __launch_bounds__(256) void k_reduce(const float* __restrict__ part,
                                                const float* __restrict__ bias,
                                                float* __restrict__ Z) {
    const int i4 = blockIdx.x * 256 + threadIdx.x;
    f32x4 s = reinterpret_cast<const f32x4*>(part)[i4];
#pragma unroll
    for (int r = 1; r < SPLITK; ++r) {
        const f32x4 p = reinterpret_cast<const f32x4*>(part + (size_t)r * BATCH * OUT_SIZE)[i4];
#pragma unroll
        for (int k = 0; k < 4; ++k) s[k] += p[k];
    }
    const f32x4 bv = reinterpret_cast<const f32x4*>(bias)[i4 & (OUT_SIZE / 4 - 1)];
    f32x4 o;
#pragma unroll
    for (int k = 0; k < 4; ++k) o[k] = fmaxf(s[k] + bv[k], 0.f);
    reinterpret_cast<f32x4*>(Z)[i4] = o;
}

// ===========================================================================
// Fallback path (round-2, known-correct) if workspace is too small
// ===========================================================================
#define SC_BLOCKS 1024
__global__ __launch_bounds__(256) void scatter_t(const int2* __restrict__ idx2,
                                                 const float* __restrict__ val,
                                                 float* __restrict__ Wt) {
    const int stride = SC_BLOCKS * 256;
    int i = blockIdx.x * 256 + threadIdx.x;
#pragma unroll 1
    for (int iter = 0; iter < NNZ / (4 * SC_BLOCKS * 256); ++iter) {
        const int2 e0 = idx2[i];
        const int2 e1 = idx2[i + stride];
        const int2 e2 = idx2[i + 2 * stride];
        const int2 e3 = idx2[i + 3 * stride];
        const float v0 = val[i], v1 = val[i + stride], v2 = val[i + 2 * stride], v3 = val[i + 3 * stride];
        atomicAdd(&Wt[e0.y * IN_SIZE + e0.x], v0);
        atomicAdd(&Wt[e1.y * IN_SIZE + e1.x], v1);
        atomicAdd(&Wt[e2.y * IN_SIZE + e2.x], v2);
        atomicAdd(&Wt[e3.y * IN_SIZE + e3.x], v3);
        i += 4 * stride;
    }
}

__global__ __launch_bounds__(256) void gemm_mfma(const float* __restrict__ X,
                                                 const float* __restrict__ Wt,
                                                 const float* __restrict__ bias,
                                                 float* __restrict__ Z) {
    const int l = threadIdx.x & 63, w = threadIdx.x >> 6;
    const int bm = blockIdx.y * 128, bn = blockIdx.x * 32;
    const int lr = l & 15, kg = (l >> 4) * 8;
    const float* pA[2];
    const float* pB[2];
#pragma unroll
    for (int mi = 0; mi < 2; ++mi) pA[mi] = X + (bm + w * 32 + mi * 16 + lr) * IN_SIZE + kg;
#pragma unroll
    for (int ni = 0; ni < 2; ++ni) pB[ni] = Wt + (bn + ni * 16 + lr) * IN_SIZE + kg;
    f32x4 acc[2][2] = {};
#pragma unroll 2
    for (int k0 = 0; k0 < IN_SIZE; k0 += 32) {
        s16x8 a[2], b[2];
#pragma unroll
        for (int mi = 0; mi < 2; ++mi) {
            const f32x4 lo = *reinterpret_cast<const f32x4*>(pA[mi]);
            const f32x4 hi = *reinterpret_cast<const f32x4*>(pA[mi] + 4);
            a[mi] = pack8(lo, hi); pA[mi] += 32;
        }
#pragma unroll
        for (int ni = 0; ni < 2; ++ni) {
            const f32x4 lo = *reinterpret_cast<const f32x4*>(pB[ni]);
            const f32x4 hi = *reinterpret_cast<const f32x4*>(pB[ni] + 4);
            b[ni] = pack8(lo, hi); pB[ni] += 32;
        }
#pragma unroll
        for (int mi = 0; mi < 2; ++mi)
#pragma unroll
            for (int ni = 0; ni < 2; ++ni)
                acc[mi][ni] = __builtin_amdgcn_mfma_f32_16x16x32_bf16(a[mi], b[ni], acc[mi][ni], 0, 0, 0);
    }
#pragma unroll
    for (int mi = 0; mi < 2; ++mi)
#pragma unroll
        for (int ni = 0; ni < 2; ++ni) {
            const int col = bn + ni * 16 + lr;
            const float bv = bias[col];
            const int r0 = bm + w * 32 + mi * 16 + ((l >> 4) << 2);
#pragma unroll
            for (int rr = 0; rr < 4; ++rr)
                Z[(r0 + rr) * OUT_SIZE + col] = fmaxf(acc[mi][ni][rr] + bv, 0.f);
        }
}

extern "C" void kernel_launch(void* const* d_in, const int* in_sizes, int n_in,
                              void* d_out, int out_size, void* d_ws, size_t ws_size,
                              hipStream_t stream) {
    const float* X    = (const float*)d_in[0];
    const int*   idx  = (const int*)d_in[1];
    const float* val  = (const float*)d_in[2];
    const float* bias = (const float*)d_in[3];
    float* Z = (float*)d_out;
    char*  ws = (char*)d_ws;

    if (ws_size >= WS_NEED) {
        s16x8*    Xb     = (s16x8*)(ws + OFF_XBF);
        short*    Wtb    = (short*)(ws + OFF_WTBF);
        float*    part   = (float*)(ws + OFF_PART);
        unsigned* binned = (unsigned*)(ws + OFF_BIN);
        unsigned* cnt    = (unsigned*)(ws + OFF_CNT);

        hipMemsetAsync(cnt, 0, (size_t)REP * NB * 4, stream);
        k_xcvt<<<(BATCH * IN_SIZE) / (256 * 8), 256, 0, stream>>>(X, Xb);
        k_bin<<<BBIN, 256, 0, stream>>>((const int4*)idx, (const float2*)val, cnt, binned);
        k_accum<<<NB, 1024, 0, stream>>>(binned, cnt, (s16x8*)Wtb);
        dim3 gg(OUT_SIZE / BN, BATCH / BM, SPLITK);
        k_gemm<<<gg, 256, 0, stream>>>((const short*)Xb, Wtb, part);
        k_reduce<<<(BATCH * OUT_SIZE) / (256 * 4), 256, 0, stream>>>(part, bias, Z);
    } else {
        float* Wt = (float*)d_ws;
        hipMemsetAsync(Wt, 0, (size_t)IN_SIZE * OUT_SIZE * sizeof(float), stream);
        scatter_t<<<SC_BLOCKS, 256, 0, stream>>>((const int2*)idx, val, Wt);
        dim3 grid(OUT_SIZE / 32, BATCH / 128);
        gemm_mfma<<<grid, 256, 0, stream>>>(X, Wt, bias, Z);
    }
}